// Round 10
// baseline (79.092 us; speedup 1.0000x reference)
//
#include <hip/hip_runtime.h>

// Chamfer distance L2 via MFMA (R10 = R9 with the REAL register-budget fix).
// Evidence across R7-R9: scratch footprint == threads x rmin-bytes (193MB
// constant), VGPR_Count pinned at 64 regardless of __launch_bounds__ 2nd arg.
// Diagnosis: backend occupancy heuristic caps arch-VGPRs at 64; AGPR->VGPR
// copies of the f32x16 accs push demand ~90 -> rmin spills to scratch; the
// ~193MB/dispatch scratch write traffic at ~3.2TB/s bounds the kernel.
// Fix: __attribute__((amdgpu_flat_work_group_size(256,256),
// amdgpu_waves_per_eu(1))) -- the function attrs the AMDGPU backend actually
// budgets registers from. Demand ~95 of 512 -> no spill possible.
// Math/structure identical to R8/R9 (proven absmax 0):
// mfma_f32_32x32x16_bf16 on 16-slot hi/lo-split bf16 kvecs; two
// orientations; per-lane fminf row-min; padded-LDS transpose epilogue;
// plain deterministic part stores.
// C/D layout: col=lane&31, row=(r&3)+8*(r>>2)+4*(lane>>5) [m74/m101].

typedef float  f32x16 __attribute__((ext_vector_type(16)));
typedef __bf16 bf16x8 __attribute__((ext_vector_type(8)));

constexpr int B  = 8;
constexpr int N  = 8192;
constexpr int BN = B * N;       // 65536 points per set
constexpr int NQ = 2 * BN;      // 131072 rows total (both directions)
constexpr int CO = 4;           // outer target chunks (part slabs)

__device__ inline ushort f2bh(float x) {            // fp32 -> bf16 RNE
  unsigned u = __float_as_uint(x);
  return (ushort)((u + 0x7FFFu + ((u >> 16) & 1u)) >> 16);
}
__device__ inline float bh2f(ushort h) { return __uint_as_float(((unsigned)h) << 16); }

// A-form: [-2xh,-2xl,-2xh,-2xl, -2yh,..., -2zh,..., wh,wl,1,1]
// B-form: [ xh,  xh,  xl,  xl,   yh, ...,  zh, ..., 1,1,wh,wl]
__global__ __launch_bounds__(256) void pack_both_kernel(
    const float* __restrict__ xyz1, const float* __restrict__ xyz2,
    ushort* __restrict__ kvA1, ushort* __restrict__ kvB1,
    ushort* __restrict__ kvA2, ushort* __restrict__ kvB2) {
  int i = blockIdx.x * 256 + threadIdx.x;   // [0, 2*BN)
  bool s1 = i < BN;
  const float* src = s1 ? xyz1 : xyz2;
  ushort* kvA = s1 ? kvA1 : kvA2;
  ushort* kvB = s1 ? kvB1 : kvB2;
  int j = s1 ? i : i - BN;
  float x = src[3 * j], y = src[3 * j + 1], z = src[3 * j + 2];
  float w = fmaf(x, x, fmaf(y, y, z * z));
  ushort xh = f2bh(x), yh = f2bh(y), zh = f2bh(z), wh = f2bh(w);
  ushort xl = f2bh(x - bh2f(xh)), yl = f2bh(y - bh2f(yh));
  ushort zl = f2bh(z - bh2f(zh)), wl = f2bh(w - bh2f(wh));
  const unsigned ONE2 = 0x3F803F80u;                 // (1.0, 1.0) bf16
  unsigned pw = (unsigned)wh | ((unsigned)wl << 16);
  {
    ushort axh = f2bh(-2.f * bh2f(xh)), axl = f2bh(-2.f * bh2f(xl));
    ushort ayh = f2bh(-2.f * bh2f(yh)), ayl = f2bh(-2.f * bh2f(yl));
    ushort azh = f2bh(-2.f * bh2f(zh)), azl = f2bh(-2.f * bh2f(zl));
    unsigned px = (unsigned)axh | ((unsigned)axl << 16);
    unsigned py = (unsigned)ayh | ((unsigned)ayl << 16);
    unsigned pz = (unsigned)azh | ((unsigned)azl << 16);
    *(uint4*)(kvA + (size_t)j * 16)     = make_uint4(px, px, py, py);
    *(uint4*)(kvA + (size_t)j * 16 + 8) = make_uint4(pz, pz, pw, ONE2);
  }
  {
    unsigned bx0 = (unsigned)xh | ((unsigned)xh << 16);
    unsigned bx1 = (unsigned)xl | ((unsigned)xl << 16);
    unsigned by0 = (unsigned)yh | ((unsigned)yh << 16);
    unsigned by1 = (unsigned)yl | ((unsigned)yl << 16);
    unsigned bz0 = (unsigned)zh | ((unsigned)zh << 16);
    unsigned bz1 = (unsigned)zl | ((unsigned)zl << 16);
    *(uint4*)(kvB + (size_t)j * 16)     = make_uint4(bx0, bx1, by0, by1);
    *(uint4*)(kvB + (size_t)j * 16 + 8) = make_uint4(bz0, bz1, ONE2, pw);
  }
}

// grid = dir(2) x b(8) x c(4) x qg(32) = 2048 blocks, qg fastest (32
// consecutive blocks stream the same 2048-target chunk -> L2-hot).
// Block: 4 waves; wave owns 64 A-rows (2 tiles of 32); sweeps 2048 targets
// staged in LDS as 2 x 1024-point halves. red aliases kb (used after all
// kb reads complete + barrier).
__global__ __attribute__((amdgpu_flat_work_group_size(256, 256),
                          amdgpu_waves_per_eu(1)))
void nn_mfma32_kernel(
    const ushort* __restrict__ kvA1, const ushort* __restrict__ kvB1,
    const ushort* __restrict__ kvA2, const ushort* __restrict__ kvB2,
    float* __restrict__ part) {
  __shared__ __align__(16) unsigned char smem[1024 * 32];  // 32 KB
  ushort* kb = (ushort*)smem;                        // [1024][16] kvecs
  float (*red)[32][36] = (float (*)[32][36])smem;    // [4][32][36] = 18 KB

  const int bid = blockIdx.x;
  const int qg  = bid & 31;
  const int c   = (bid >> 5) & 3;
  const int b   = (bid >> 7) & 7;
  const int dir = (bid >> 10) & 1;
  const ushort* __restrict__ kvA = dir ? kvA2 : kvA1;
  const ushort* __restrict__ kvB = dir ? kvB1 : kvB2;

  const int tid = threadIdx.x;
  const int w = tid >> 6, lane = tid & 63;
  const int cl = lane & 31, hi = lane >> 5;

  // A fragments: 2 tiles x 32 rows; lane holds row cl, k-half hi
  const int qbase = b * N + qg * 256 + w * 64;
  bf16x8 af[2];
  #pragma unroll
  for (int a = 0; a < 2; ++a)
    af[a] = *(const bf16x8*)(kvA + (size_t)(qbase + a * 32 + cl) * 16 + hi * 8);

  float rmin[2][16];
  #pragma unroll
  for (int a = 0; a < 2; ++a)
    #pragma unroll
    for (int r = 0; r < 16; ++r) rmin[a][r] = 3.4e38f;

  const f32x16 cz = {0.f, 0.f, 0.f, 0.f, 0.f, 0.f, 0.f, 0.f,
                     0.f, 0.f, 0.f, 0.f, 0.f, 0.f, 0.f, 0.f};
  const int tbase = b * N + c * 2048;

  #pragma unroll 1
  for (int half = 0; half < 2; ++half) {
    if (half) __syncthreads();                       // all waves done with kb
    {   // stage 1024 targets (32 KB)
      const uint4* src = (const uint4*)(kvB + (size_t)(tbase + half * 1024) * 16);
      uint4* dst = (uint4*)kb;
      #pragma unroll
      for (int i = 0; i < 8; ++i) dst[tid + i * 256] = src[tid + i * 256];
    }
    __syncthreads();

    #pragma unroll 1
    for (int jp = 0; jp < 16; ++jp) {               // 2 target tiles per iter
      const ushort* kp = kb + (jp * 64 + cl) * 16 + hi * 8;
      bf16x8 bf0 = *(const bf16x8*)(kp);
      bf16x8 bf1 = *(const bf16x8*)(kp + 32 * 16);
      #pragma unroll
      for (int a = 0; a < 2; ++a) {
        f32x16 acc0 = __builtin_amdgcn_mfma_f32_32x32x16_bf16(af[a], bf0, cz, 0, 0, 0);
        f32x16 acc1 = __builtin_amdgcn_mfma_f32_32x32x16_bf16(af[a], bf1, cz, 0, 0, 0);
        #pragma unroll
        for (int r = 0; r < 16; ++r)
          rmin[a][r] = fminf(rmin[a][r], fminf(acc0[r], acc1[r]));
      }
    }
  }

  // epilogue: per a-tile, transpose via padded LDS (aliases kb; guarded by
  // __syncthreads), per-row fold, plain deterministic store
  #pragma unroll 1
  for (int a = 0; a < 2; ++a) {
    __syncthreads();                                 // kb reads / red reuse done
    #pragma unroll
    for (int r = 0; r < 16; ++r) {
      int row = (r & 3) + 8 * (r >> 2) + 4 * hi;     // m74/m101 C/D layout
      red[w][row][cl] = rmin[a][r];
    }
    __syncthreads();
    if (lane < 32) {
      float m = 3.4e38f;
      #pragma unroll
      for (int i = 0; i < 8; ++i) {
        float4 v = *(const float4*)&red[w][lane][i * 4];
        m = fminf(m, fminf(fminf(v.x, v.y), fminf(v.z, v.w)));
      }
      part[(size_t)c * NQ + dir * BN + qbase + a * 32 + lane] = m;
    }
  }
}

__global__ __launch_bounds__(256) void reduce_final_kernel(
    const float* __restrict__ part, float* __restrict__ blocksums) {
  int gq = blockIdx.x * 256 + threadIdx.x;   // [0, NQ)
  float v = part[gq];
  #pragma unroll
  for (int cc = 1; cc < CO; ++cc) v = fminf(v, part[(size_t)cc * NQ + gq]);
  #pragma unroll
  for (int off = 32; off > 0; off >>= 1) v += __shfl_down(v, off);
  __shared__ float ssum[4];
  const int lane = threadIdx.x & 63, wid = threadIdx.x >> 6;
  if (lane == 0) ssum[wid] = v;
  __syncthreads();
  if (threadIdx.x == 0)
    blocksums[blockIdx.x] = ssum[0] + ssum[1] + ssum[2] + ssum[3];
}

__global__ __launch_bounds__(512) void finalize_sums_kernel(
    const float* __restrict__ blocksums, float* __restrict__ out) {
  float v = blocksums[threadIdx.x];
  #pragma unroll
  for (int off = 32; off > 0; off >>= 1) v += __shfl_down(v, off);
  __shared__ float ssum[8];
  const int lane = threadIdx.x & 63, wid = threadIdx.x >> 6;
  if (lane == 0) ssum[wid] = v;
  __syncthreads();
  if (threadIdx.x == 0) {
    float s = 0.f;
    #pragma unroll
    for (int w = 0; w < 8; ++w) s += ssum[w];
    out[0] = s * (1.0f / 65536.0f);   // mean1 + mean2 (B*N == B*M)
  }
}

// ---------- round-1 proven fallback (if ws too small) ----------
__global__ __launch_bounds__(256) void pack4_kernel(
    const float* __restrict__ xyz1, const float* __restrict__ xyz2,
    float4* __restrict__ p1, float4* __restrict__ p2) {
  int i = blockIdx.x * 256 + threadIdx.x;
  const float* s = (i < BN) ? xyz1 : xyz2;
  float4* d      = (i < BN) ? p1 : p2;
  int j          = (i < BN) ? i : (i - BN);
  float x = s[3 * j], y = s[3 * j + 1], z = s[3 * j + 2];
  d[j] = make_float4(x, y, z, fmaf(x, x, fmaf(y, y, z * z)));
}

__global__ __launch_bounds__(256) void nn_packed_kernel(
    const float4* __restrict__ p1, const float4* __restrict__ p2,
    float* __restrict__ blocksums) {
  const int bid   = blockIdx.x;
  const int dir   = bid >> 8;
  const int idx   = bid & 255;
  const int b     = idx >> 5;
  const int chunk = idx & 31;
  const float4* __restrict__ q = (dir ? p2 : p1) + b * N + chunk * 256;
  const float4* __restrict__ t = (dir ? p1 : p2) + b * N;

  float4 qv = q[threadIdx.x];
  const float qx = -2.0f * qv.x, qy = -2.0f * qv.y, qz = -2.0f * qv.z;

  float mn0 = 3.4e38f, mn1 = 3.4e38f, mn2 = 3.4e38f, mn3 = 3.4e38f;
  #pragma unroll 2
  for (int m = 0; m < N; m += 4) {
    float4 t0 = t[m + 0], t1 = t[m + 1], t2 = t[m + 2], t3 = t[m + 3];
    float d0 = fmaf(qx, t0.x, fmaf(qy, t0.y, fmaf(qz, t0.z, t0.w)));
    float d1 = fmaf(qx, t1.x, fmaf(qy, t1.y, fmaf(qz, t1.z, t1.w)));
    float d2 = fmaf(qx, t2.x, fmaf(qy, t2.y, fmaf(qz, t2.z, t2.w)));
    float d3 = fmaf(qx, t3.x, fmaf(qy, t3.y, fmaf(qz, t3.z, t3.w)));
    mn0 = fminf(mn0, d0); mn1 = fminf(mn1, d1);
    mn2 = fminf(mn2, d2); mn3 = fminf(mn3, d3);
  }
  float v = qv.w + fminf(fminf(mn0, mn1), fminf(mn2, mn3));

  #pragma unroll
  for (int off = 32; off > 0; off >>= 1) v += __shfl_down(v, off);
  __shared__ float ssum[4];
  const int lane = threadIdx.x & 63, wid = threadIdx.x >> 6;
  if (lane == 0) ssum[wid] = v;
  __syncthreads();
  if (threadIdx.x == 0)
    blocksums[bid] = ssum[0] + ssum[1] + ssum[2] + ssum[3];
}

extern "C" void kernel_launch(void* const* d_in, const int* in_sizes, int n_in,
                              void* d_out, int out_size, void* d_ws, size_t ws_size,
                              hipStream_t stream) {
  const float* xyz1 = (const float*)d_in[0];
  const float* xyz2 = (const float*)d_in[1];
  float* out = (float*)d_out;

  // ws: kvA1,kvB1,kvA2,kvB2 (2MB each) | part (CO*NQ f32 = 2MB) | blocksums
  ushort* kvA1 = (ushort*)d_ws;
  ushort* kvB1 = kvA1 + (size_t)BN * 16;
  ushort* kvA2 = kvB1 + (size_t)BN * 16;
  ushort* kvB2 = kvA2 + (size_t)BN * 16;
  float* part = (float*)(kvB2 + (size_t)BN * 16);
  float* blocksums = part + (size_t)CO * NQ;
  const size_t need = (size_t)BN * 16 * 2 * 4 + (size_t)CO * NQ * 4 +
                      512 * sizeof(float);

  if (ws_size >= need) {
    pack_both_kernel<<<(2 * BN) / 256, 256, 0, stream>>>(
        xyz1, xyz2, kvA1, kvB1, kvA2, kvB2);
    nn_mfma32_kernel<<<2048, 256, 0, stream>>>(kvA1, kvB1, kvA2, kvB2, part);
    reduce_final_kernel<<<NQ / 256, 256, 0, stream>>>(part, blocksums);
    finalize_sums_kernel<<<1, 512, 0, stream>>>(blocksums, out);
  } else {
    float4* p1 = (float4*)d_ws;
    float4* p2 = p1 + BN;
    float* bsum = (float*)(p2 + BN);
    pack4_kernel<<<(2 * BN) / 256, 256, 0, stream>>>(xyz1, xyz2, p1, p2);
    nn_packed_kernel<<<512, 256, 0, stream>>>(p1, p2, bsum);
    finalize_sums_kernel<<<1, 512, 0, stream>>>(bsum, out);
  }
}

// Round 11
// 49.192 us; speedup vs baseline: 1.6078x; 1.6078x over previous
//
#include <hip/hip_runtime.h>

// Chamfer distance L2 via MFMA (R11 = R9 with the ACTUAL spill fix).
// Root cause found (rule #20): the epilogue's `#pragma unroll 1` a-loop
// indexed rmin[a][r] with RUNTIME a -> the whole rmin array was allocated
// in scratch (localMem), and the main loop's read-modify-write of rmin went
// through scratch: ~190MB/dispatch HBM writes, insensitive to every
// launch-bounds knob (R8/R9/R10), VGPR_Count=64 because register demand
// was artificially LOW (rmin lived in memory). Fix: fully unroll the
// epilogue a-loop so all rmin indexing is compile-time -> rmin in VGPRs.
// Math/structure identical to R8/R9/R10 (proven absmax 0):
// mfma_f32_32x32x16_bf16 on 16-slot hi/lo-split bf16 kvecs; two
// orientations; per-lane fminf row-min; padded-LDS transpose epilogue;
// plain deterministic part stores.
// C/D layout: col=lane&31, row=(r&3)+8*(r>>2)+4*(lane>>5) [m74/m101].

typedef float  f32x16 __attribute__((ext_vector_type(16)));
typedef __bf16 bf16x8 __attribute__((ext_vector_type(8)));

constexpr int B  = 8;
constexpr int N  = 8192;
constexpr int BN = B * N;       // 65536 points per set
constexpr int NQ = 2 * BN;      // 131072 rows total (both directions)
constexpr int CO = 4;           // outer target chunks (part slabs)

__device__ inline ushort f2bh(float x) {            // fp32 -> bf16 RNE
  unsigned u = __float_as_uint(x);
  return (ushort)((u + 0x7FFFu + ((u >> 16) & 1u)) >> 16);
}
__device__ inline float bh2f(ushort h) { return __uint_as_float(((unsigned)h) << 16); }

// A-form: [-2xh,-2xl,-2xh,-2xl, -2yh,..., -2zh,..., wh,wl,1,1]
// B-form: [ xh,  xh,  xl,  xl,   yh, ...,  zh, ..., 1,1,wh,wl]
__global__ __launch_bounds__(256) void pack_both_kernel(
    const float* __restrict__ xyz1, const float* __restrict__ xyz2,
    ushort* __restrict__ kvA1, ushort* __restrict__ kvB1,
    ushort* __restrict__ kvA2, ushort* __restrict__ kvB2) {
  int i = blockIdx.x * 256 + threadIdx.x;   // [0, 2*BN)
  bool s1 = i < BN;
  const float* src = s1 ? xyz1 : xyz2;
  ushort* kvA = s1 ? kvA1 : kvA2;
  ushort* kvB = s1 ? kvB1 : kvB2;
  int j = s1 ? i : i - BN;
  float x = src[3 * j], y = src[3 * j + 1], z = src[3 * j + 2];
  float w = fmaf(x, x, fmaf(y, y, z * z));
  ushort xh = f2bh(x), yh = f2bh(y), zh = f2bh(z), wh = f2bh(w);
  ushort xl = f2bh(x - bh2f(xh)), yl = f2bh(y - bh2f(yh));
  ushort zl = f2bh(z - bh2f(zh)), wl = f2bh(w - bh2f(wh));
  const unsigned ONE2 = 0x3F803F80u;                 // (1.0, 1.0) bf16
  unsigned pw = (unsigned)wh | ((unsigned)wl << 16);
  {
    ushort axh = f2bh(-2.f * bh2f(xh)), axl = f2bh(-2.f * bh2f(xl));
    ushort ayh = f2bh(-2.f * bh2f(yh)), ayl = f2bh(-2.f * bh2f(yl));
    ushort azh = f2bh(-2.f * bh2f(zh)), azl = f2bh(-2.f * bh2f(zl));
    unsigned px = (unsigned)axh | ((unsigned)axl << 16);
    unsigned py = (unsigned)ayh | ((unsigned)ayl << 16);
    unsigned pz = (unsigned)azh | ((unsigned)azl << 16);
    *(uint4*)(kvA + (size_t)j * 16)     = make_uint4(px, px, py, py);
    *(uint4*)(kvA + (size_t)j * 16 + 8) = make_uint4(pz, pz, pw, ONE2);
  }
  {
    unsigned bx0 = (unsigned)xh | ((unsigned)xh << 16);
    unsigned bx1 = (unsigned)xl | ((unsigned)xl << 16);
    unsigned by0 = (unsigned)yh | ((unsigned)yh << 16);
    unsigned by1 = (unsigned)yl | ((unsigned)yl << 16);
    unsigned bz0 = (unsigned)zh | ((unsigned)zh << 16);
    unsigned bz1 = (unsigned)zl | ((unsigned)zl << 16);
    *(uint4*)(kvB + (size_t)j * 16)     = make_uint4(bx0, bx1, by0, by1);
    *(uint4*)(kvB + (size_t)j * 16 + 8) = make_uint4(bz0, bz1, ONE2, pw);
  }
}

// grid = dir(2) x b(8) x c(4) x qg(32) = 2048 blocks, qg fastest (32
// consecutive blocks stream the same 2048-target chunk -> L2-hot).
// Block: 4 waves; wave owns 64 A-rows (2 tiles of 32); sweeps 2048 targets
// staged in LDS as 2 x 1024-point halves. red aliases kb (used after all
// kb reads complete + barrier).
__global__ __launch_bounds__(256, 2) void nn_mfma32_kernel(
    const ushort* __restrict__ kvA1, const ushort* __restrict__ kvB1,
    const ushort* __restrict__ kvA2, const ushort* __restrict__ kvB2,
    float* __restrict__ part) {
  __shared__ __align__(16) unsigned char smem[1024 * 32];  // 32 KB
  ushort* kb = (ushort*)smem;                        // [1024][16] kvecs
  float (*red)[32][36] = (float (*)[32][36])smem;    // [4][32][36] = 18 KB

  const int bid = blockIdx.x;
  const int qg  = bid & 31;
  const int c   = (bid >> 5) & 3;
  const int b   = (bid >> 7) & 7;
  const int dir = (bid >> 10) & 1;
  const ushort* __restrict__ kvA = dir ? kvA2 : kvA1;
  const ushort* __restrict__ kvB = dir ? kvB1 : kvB2;

  const int tid = threadIdx.x;
  const int w = tid >> 6, lane = tid & 63;
  const int cl = lane & 31, hi = lane >> 5;

  // A fragments: 2 tiles x 32 rows; lane holds row cl, k-half hi
  const int qbase = b * N + qg * 256 + w * 64;
  bf16x8 af[2];
  #pragma unroll
  for (int a = 0; a < 2; ++a)
    af[a] = *(const bf16x8*)(kvA + (size_t)(qbase + a * 32 + cl) * 16 + hi * 8);

  float rmin[2][16];
  #pragma unroll
  for (int a = 0; a < 2; ++a)
    #pragma unroll
    for (int r = 0; r < 16; ++r) rmin[a][r] = 3.4e38f;

  const f32x16 cz = {0.f, 0.f, 0.f, 0.f, 0.f, 0.f, 0.f, 0.f,
                     0.f, 0.f, 0.f, 0.f, 0.f, 0.f, 0.f, 0.f};
  const int tbase = b * N + c * 2048;

  #pragma unroll 1
  for (int half = 0; half < 2; ++half) {
    if (half) __syncthreads();                       // all waves done with kb
    {   // stage 1024 targets (32 KB)
      const uint4* src = (const uint4*)(kvB + (size_t)(tbase + half * 1024) * 16);
      uint4* dst = (uint4*)kb;
      #pragma unroll
      for (int i = 0; i < 8; ++i) dst[tid + i * 256] = src[tid + i * 256];
    }
    __syncthreads();

    #pragma unroll 1
    for (int jp = 0; jp < 16; ++jp) {               // 2 target tiles per iter
      const ushort* kp = kb + (jp * 64 + cl) * 16 + hi * 8;
      bf16x8 bf0 = *(const bf16x8*)(kp);
      bf16x8 bf1 = *(const bf16x8*)(kp + 32 * 16);
      #pragma unroll
      for (int a = 0; a < 2; ++a) {
        f32x16 acc0 = __builtin_amdgcn_mfma_f32_32x32x16_bf16(af[a], bf0, cz, 0, 0, 0);
        f32x16 acc1 = __builtin_amdgcn_mfma_f32_32x32x16_bf16(af[a], bf1, cz, 0, 0, 0);
        #pragma unroll
        for (int r = 0; r < 16; ++r)
          rmin[a][r] = fminf(rmin[a][r], fminf(acc0[r], acc1[r]));
      }
    }
  }

  // epilogue: per a-tile, transpose via padded LDS (aliases kb; guarded by
  // __syncthreads), per-row fold, plain deterministic store.
  // FULLY UNROLLED (rule #20): rmin[a][r] must be compile-time-indexed,
  // else the whole array lives in scratch (R7-R10's 190MB write leak).
  #pragma unroll
  for (int a = 0; a < 2; ++a) {
    __syncthreads();                                 // kb reads / red reuse done
    #pragma unroll
    for (int r = 0; r < 16; ++r) {
      int row = (r & 3) + 8 * (r >> 2) + 4 * hi;     // m74/m101 C/D layout
      red[w][row][cl] = rmin[a][r];
    }
    __syncthreads();
    if (lane < 32) {
      float m = 3.4e38f;
      #pragma unroll
      for (int i = 0; i < 8; ++i) {
        float4 v = *(const float4*)&red[w][lane][i * 4];
        m = fminf(m, fminf(fminf(v.x, v.y), fminf(v.z, v.w)));
      }
      part[(size_t)c * NQ + dir * BN + qbase + a * 32 + lane] = m;
    }
  }
}

__global__ __launch_bounds__(256) void reduce_final_kernel(
    const float* __restrict__ part, float* __restrict__ blocksums) {
  int gq = blockIdx.x * 256 + threadIdx.x;   // [0, NQ)
  float v = part[gq];
  #pragma unroll
  for (int cc = 1; cc < CO; ++cc) v = fminf(v, part[(size_t)cc * NQ + gq]);
  #pragma unroll
  for (int off = 32; off > 0; off >>= 1) v += __shfl_down(v, off);
  __shared__ float ssum[4];
  const int lane = threadIdx.x & 63, wid = threadIdx.x >> 6;
  if (lane == 0) ssum[wid] = v;
  __syncthreads();
  if (threadIdx.x == 0)
    blocksums[blockIdx.x] = ssum[0] + ssum[1] + ssum[2] + ssum[3];
}

__global__ __launch_bounds__(512) void finalize_sums_kernel(
    const float* __restrict__ blocksums, float* __restrict__ out) {
  float v = blocksums[threadIdx.x];
  #pragma unroll
  for (int off = 32; off > 0; off >>= 1) v += __shfl_down(v, off);
  __shared__ float ssum[8];
  const int lane = threadIdx.x & 63, wid = threadIdx.x >> 6;
  if (lane == 0) ssum[wid] = v;
  __syncthreads();
  if (threadIdx.x == 0) {
    float s = 0.f;
    #pragma unroll
    for (int w = 0; w < 8; ++w) s += ssum[w];
    out[0] = s * (1.0f / 65536.0f);   // mean1 + mean2 (B*N == B*M)
  }
}

// ---------- round-1 proven fallback (if ws too small) ----------
__global__ __launch_bounds__(256) void pack4_kernel(
    const float* __restrict__ xyz1, const float* __restrict__ xyz2,
    float4* __restrict__ p1, float4* __restrict__ p2) {
  int i = blockIdx.x * 256 + threadIdx.x;
  const float* s = (i < BN) ? xyz1 : xyz2;
  float4* d      = (i < BN) ? p1 : p2;
  int j          = (i < BN) ? i : (i - BN);
  float x = s[3 * j], y = s[3 * j + 1], z = s[3 * j + 2];
  d[j] = make_float4(x, y, z, fmaf(x, x, fmaf(y, y, z * z)));
}

__global__ __launch_bounds__(256) void nn_packed_kernel(
    const float4* __restrict__ p1, const float4* __restrict__ p2,
    float* __restrict__ blocksums) {
  const int bid   = blockIdx.x;
  const int dir   = bid >> 8;
  const int idx   = bid & 255;
  const int b     = idx >> 5;
  const int chunk = idx & 31;
  const float4* __restrict__ q = (dir ? p2 : p1) + b * N + chunk * 256;
  const float4* __restrict__ t = (dir ? p1 : p2) + b * N;

  float4 qv = q[threadIdx.x];
  const float qx = -2.0f * qv.x, qy = -2.0f * qv.y, qz = -2.0f * qv.z;

  float mn0 = 3.4e38f, mn1 = 3.4e38f, mn2 = 3.4e38f, mn3 = 3.4e38f;
  #pragma unroll 2
  for (int m = 0; m < N; m += 4) {
    float4 t0 = t[m + 0], t1 = t[m + 1], t2 = t[m + 2], t3 = t[m + 3];
    float d0 = fmaf(qx, t0.x, fmaf(qy, t0.y, fmaf(qz, t0.z, t0.w)));
    float d1 = fmaf(qx, t1.x, fmaf(qy, t1.y, fmaf(qz, t1.z, t1.w)));
    float d2 = fmaf(qx, t2.x, fmaf(qy, t2.y, fmaf(qz, t2.z, t2.w)));
    float d3 = fmaf(qx, t3.x, fmaf(qy, t3.y, fmaf(qz, t3.z, t3.w)));
    mn0 = fminf(mn0, d0); mn1 = fminf(mn1, d1);
    mn2 = fminf(mn2, d2); mn3 = fminf(mn3, d3);
  }
  float v = qv.w + fminf(fminf(mn0, mn1), fminf(mn2, mn3));

  #pragma unroll
  for (int off = 32; off > 0; off >>= 1) v += __shfl_down(v, off);
  __shared__ float ssum[4];
  const int lane = threadIdx.x & 63, wid = threadIdx.x >> 6;
  if (lane == 0) ssum[wid] = v;
  __syncthreads();
  if (threadIdx.x == 0)
    blocksums[bid] = ssum[0] + ssum[1] + ssum[2] + ssum[3];
}

extern "C" void kernel_launch(void* const* d_in, const int* in_sizes, int n_in,
                              void* d_out, int out_size, void* d_ws, size_t ws_size,
                              hipStream_t stream) {
  const float* xyz1 = (const float*)d_in[0];
  const float* xyz2 = (const float*)d_in[1];
  float* out = (float*)d_out;

  // ws: kvA1,kvB1,kvA2,kvB2 (2MB each) | part (CO*NQ f32 = 2MB) | blocksums
  ushort* kvA1 = (ushort*)d_ws;
  ushort* kvB1 = kvA1 + (size_t)BN * 16;
  ushort* kvA2 = kvB1 + (size_t)BN * 16;
  ushort* kvB2 = kvA2 + (size_t)BN * 16;
  float* part = (float*)(kvB2 + (size_t)BN * 16);
  float* blocksums = part + (size_t)CO * NQ;
  const size_t need = (size_t)BN * 16 * 2 * 4 + (size_t)CO * NQ * 4 +
                      512 * sizeof(float);

  if (ws_size >= need) {
    pack_both_kernel<<<(2 * BN) / 256, 256, 0, stream>>>(
        xyz1, xyz2, kvA1, kvB1, kvA2, kvB2);
    nn_mfma32_kernel<<<2048, 256, 0, stream>>>(kvA1, kvB1, kvA2, kvB2, part);
    reduce_final_kernel<<<NQ / 256, 256, 0, stream>>>(part, blocksums);
    finalize_sums_kernel<<<1, 512, 0, stream>>>(blocksums, out);
  } else {
    float4* p1 = (float4*)d_ws;
    float4* p2 = p1 + BN;
    float* bsum = (float*)(p2 + BN);
    pack4_kernel<<<(2 * BN) / 256, 256, 0, stream>>>(xyz1, xyz2, p1, p2);
    nn_packed_kernel<<<512, 256, 0, stream>>>(p1, p2, bsum);
    finalize_sums_kernel<<<1, 512, 0, stream>>>(bsum, out);
  }
}